// Round 1
// baseline (67.392 us; speedup 1.0000x reference)
//
#include <hip/hip_runtime.h>
#include <hip/hip_bf16.h>
#include <stdint.h>

#define BATCH 8192
#define DIM   1024

typedef __attribute__((ext_vector_type(4))) float f32x4;
typedef __attribute__((ext_vector_type(8))) short bf16x8;
typedef __attribute__((ext_vector_type(4))) unsigned short u16x4;

#define AS1(p) ((const __attribute__((address_space(1))) void*)(p))
#define AS3(p) ((__attribute__((address_space(3))) void*)(p))

__device__ __forceinline__ unsigned short f2bf(float f) {
    union { float f; unsigned int u; } v; v.f = f;
    unsigned int u = v.u;
    u += 0x7fffu + ((u >> 16) & 1u);   // round-to-nearest-even
    return (unsigned short)(u >> 16);
}

// ---------------------------------------------------------------------------
// Kernel 1: elementwise prep.
//   base = -x + u*sig   -> out0 (f32)
//   0                   -> out2
//   sig (bf16)          -> ws
// ---------------------------------------------------------------------------
__global__ __launch_bounds__(256) void prep_kernel(
    const float* __restrict__ x, const float* __restrict__ ex,
    const float* __restrict__ W, const float* __restrict__ tgt,
    float* __restrict__ out0, float* __restrict__ out2,
    unsigned short* __restrict__ sigb)
{
    int idx  = blockIdx.x * 256 + threadIdx.x;   // vec4 index, grid exact
    int col4 = idx & (DIM / 4 - 1);

    f32x4 xv = ((const f32x4*)x)[idx];
    f32x4 ev = ((const f32x4*)ex)[idx];
    f32x4 wv = ((const f32x4*)W)[idx];
    f32x4 tv = ((const f32x4*)tgt)[col4];

    f32x4 base;
    u16x4 sb;
#pragma unroll
    for (int i = 0; i < 4; ++i) {
        float xi = xv[i], ti = tv[i];
        float b_ast = ti * ti / (1.0f + ti * ti);
        float u = -(wv[i] * (xi + ev[i] - ti)) * b_ast;
        float s = xi * xi / (1.0f + xi * xi);
        base[i] = -xi + u * s;
        sb[i] = f2bf(s);
    }
    ((f32x4*)out0)[idx] = base;
    ((f32x4*)out2)[idx] = f32x4{0.f, 0.f, 0.f, 0.f};
    ((u16x4*)sigb)[idx] = sb;
}

// ---------------------------------------------------------------------------
// Kernel 2: convert A (f32 [D][D]) to bf16
// ---------------------------------------------------------------------------
__global__ __launch_bounds__(256) void convA_kernel(
    const float* __restrict__ A, unsigned short* __restrict__ Ab)
{
    int idx = blockIdx.x * 256 + threadIdx.x;    // vec4 index, grid exact
    f32x4 av = ((const f32x4*)A)[idx];
    u16x4 ab;
#pragma unroll
    for (int i = 0; i < 4; ++i) ab[i] = f2bf(av[i]);
    ((u16x4*)Ab)[idx] = ab;
}

// ---------------------------------------------------------------------------
// Kernel 3: C = sig @ A^T (bf16 MFMA), epilogue dx = base + C.
//   out0 <- dx, out1 <- -dx
// m97 structure: 128x128 tile, BK=64, 4 waves (2x2 of 64x64), 16x16x32 MFMA,
// global_load_lds width=16 with pre-swizzled source (linear LDS dest),
// XOR-swizzled ds_read_b128 to kill the stride-128B bank conflict.
// ---------------------------------------------------------------------------
#define BM 128
#define BN 128
#define BK 64

__global__ __launch_bounds__(256) void gemm_kernel(
    const unsigned short* __restrict__ Sg,   // sig bf16 [BATCH][DIM]
    const unsigned short* __restrict__ Ab,   // A   bf16 [DIM][DIM]
    float* __restrict__ out0, float* __restrict__ out1)
{
    __shared__ char lds[(BM * BK + BN * BK) * 2];  // 32 KiB: As | Bs
    char* As = lds;
    char* Bs = lds + BM * BK * 2;

    const int nbn = DIM / BN;                // 8
    const int bm = blockIdx.x / nbn;
    const int bn = blockIdx.x % nbn;

    const int tid  = threadIdx.x;
    const int lane = tid & 63;
    const int wid  = tid >> 6;               // 0..3
    const int wr   = wid >> 1;               // 0..1
    const int wc   = wid & 1;                // 0..1

    // ---- staging addresses (global source carries the swizzle; LDS linear)
    // chunk = wid*4 + j covers 8 rows of the tile; lane i -> row chunk*8+(i>>3),
    // physical col (i&7)*16 bytes; source logical col = physical ^ ((row&7)<<4)
    const int swz = (((lane & 7) ^ (lane >> 3)) << 4);
    const char* gA = (const char*)Sg +
        ((size_t)(bm * BM + wid * 32 + (lane >> 3)) * DIM) * 2 + swz;
    const char* gB = (const char*)Ab +
        ((size_t)(bn * BN + wid * 32 + (lane >> 3)) * DIM) * 2 + swz;
    char* lA = As + wid * 4 * 1024;
    char* lB = Bs + wid * 4 * 1024;

    // ---- fragment read addresses
    const int arow  = wr * 64 + (lane & 15);
    const int brow  = wc * 64 + (lane & 15);
    const int rd_sw = (lane & 7) << 4;       // read-side XOR (row&7)<<4
    const int cb0   = (lane >> 4) << 4;      // k-group byte offset

    f32x4 acc[4][4];
#pragma unroll
    for (int mi = 0; mi < 4; ++mi)
#pragma unroll
        for (int ni = 0; ni < 4; ++ni)
            acc[mi][ni] = f32x4{0.f, 0.f, 0.f, 0.f};

    for (int k0 = 0; k0 < DIM; k0 += BK) {
        __syncthreads();   // previous iter's ds_reads done before overwrite
#pragma unroll
        for (int j = 0; j < 4; ++j) {
            __builtin_amdgcn_global_load_lds(AS1(gA + (size_t)j * (8 * DIM * 2) + k0 * 2),
                                             AS3(lA + j * 1024), 16, 0, 0);
            __builtin_amdgcn_global_load_lds(AS1(gB + (size_t)j * (8 * DIM * 2) + k0 * 2),
                                             AS3(lB + j * 1024), 16, 0, 0);
        }
        __syncthreads();   // compiler drains vmcnt before barrier

#pragma unroll
        for (int kk = 0; kk < 2; ++kk) {
            bf16x8 af[4], bfr[4];
#pragma unroll
            for (int mi = 0; mi < 4; ++mi)
                af[mi] = *(const bf16x8*)(As + (arow + mi * 16) * 128 +
                                          ((cb0 + kk * 64) ^ rd_sw));
#pragma unroll
            for (int ni = 0; ni < 4; ++ni)
                bfr[ni] = *(const bf16x8*)(Bs + (brow + ni * 16) * 128 +
                                           ((cb0 + kk * 64) ^ rd_sw));
#pragma unroll
            for (int mi = 0; mi < 4; ++mi)
#pragma unroll
                for (int ni = 0; ni < 4; ++ni)
                    acc[mi][ni] = __builtin_amdgcn_mfma_f32_16x16x32_bf16(
                        af[mi], bfr[ni], acc[mi][ni], 0, 0, 0);
        }
    }

    // ---- epilogue: dx = base + C; out0 = dx, out1 = -dx
    const int col0  = bn * BN + wc * 64 + (lane & 15);
    const int row00 = bm * BM + wr * 64 + ((lane >> 4) << 2);
#pragma unroll
    for (int mi = 0; mi < 4; ++mi) {
#pragma unroll
        for (int ni = 0; ni < 4; ++ni) {
            const int col = col0 + ni * 16;
#pragma unroll
            for (int r = 0; r < 4; ++r) {
                size_t idx = (size_t)(row00 + mi * 16 + r) * DIM + col;
                float dx = out0[idx] + acc[mi][ni][r];
                out0[idx] = dx;
                out1[idx] = -dx;
            }
        }
    }
}

// ---------------------------------------------------------------------------
extern "C" void kernel_launch(void* const* d_in, const int* in_sizes, int n_in,
                              void* d_out, int out_size, void* d_ws, size_t ws_size,
                              hipStream_t stream)
{
    const float* x   = (const float*)d_in[0];
    const float* ex  = (const float*)d_in[1];
    const float* W   = (const float*)d_in[2];
    const float* A   = (const float*)d_in[3];
    const float* tgt = (const float*)d_in[4];

    float* out0 = (float*)d_out;
    float* out1 = out0 + (size_t)BATCH * DIM;
    float* out2 = out1 + (size_t)BATCH * DIM;

    unsigned short* sigb = (unsigned short*)d_ws;                              // 16 MiB
    unsigned short* Abf  = (unsigned short*)((char*)d_ws + (size_t)BATCH * DIM * 2); // 2 MiB

    prep_kernel<<<BATCH * DIM / 4 / 256, 256, 0, stream>>>(x, ex, W, tgt, out0, out2, sigb);
    convA_kernel<<<DIM * DIM / 4 / 256, 256, 0, stream>>>(A, Abf);
    gemm_kernel<<<(BATCH / BM) * (DIM / BN), 256, 0, stream>>>(sigb, Abf, out0, out1);
}